// Round 16
// baseline (225.079 us; speedup 1.0000x reference)
//
#include <hip/hip_runtime.h>
#include <math.h>

#define S_LEN 2048
#define NBATCH 2
#define DMODEL 1024
#define PDIM 4480   // 2*2048 + 2*128 + 3*32 + 32
#define DI 2048
#define NH 32
#define HD 64
#define DS 128
#define NA 32
#define CHK 64
#define NC (S_LEN / CHK)   // 32 chunks per batch
#define ZV 4096            // z|v bf16 columns
#define PS 384             // fp32 scalar columns (B,C,dt,A,trap,ang)
// projS column offsets (proj col - 4096)
#define PS_B 0
#define PS_C 128
#define PS_DT 256
#define PS_A 288
#define PS_TRAP 320
#define PS_ANG 352

typedef __attribute__((ext_vector_type(8))) short s8v;
typedef __attribute__((ext_vector_type(4))) float f4v;

__device__ __forceinline__ float softplus_f(float x) {
    return x > 20.f ? x : log1pf(expf(x));
}

__device__ __forceinline__ ushort f2bf(float f) {
    unsigned u = __float_as_uint(f);
    unsigned r = (u + 0x7fffu + ((u >> 16) & 1u)) >> 16;
    return (ushort)r;
}

__device__ __forceinline__ uint4 pack8(const float* f) {
    uint4 o;
    o.x = (unsigned)f2bf(f[0]) | ((unsigned)f2bf(f[1]) << 16);
    o.y = (unsigned)f2bf(f[2]) | ((unsigned)f2bf(f[3]) << 16);
    o.z = (unsigned)f2bf(f[4]) | ((unsigned)f2bf(f[5]) << 16);
    o.w = (unsigned)f2bf(f[6]) | ((unsigned)f2bf(f[7]) << 16);
    return o;
}

__device__ __forceinline__ float bf2f(ushort u) {
    return __uint_as_float(((unsigned)u) << 16);
}
__device__ __forceinline__ float bf_lo(unsigned u) { return __uint_as_float(u << 16); }
__device__ __forceinline__ float bf_hi(unsigned u) { return __uint_as_float(u & 0xffff0000u); }

__device__ __forceinline__ void unpack8(uint4 a, float* f) {
    f[0] = bf_lo(a.x); f[1] = bf_hi(a.x);
    f[2] = bf_lo(a.y); f[3] = bf_hi(a.y);
    f[4] = bf_lo(a.z); f[5] = bf_hi(a.z);
    f[6] = bf_lo(a.w); f[7] = bf_hi(a.w);
}

// ---------------------------------------------------------------------------
// Fused fp32 -> bf16 swizzled conversion for x, W_in, W_out (one launch).
// ---------------------------------------------------------------------------
#define NCX  524288   // 4096*1024/8
#define NCWI 573440   // 4480*1024/8
#define NCWO 262144   // 2048*1024/8
__global__ __launch_bounds__(256)
void f2bf_all(const float* __restrict__ x, const float* __restrict__ wi,
              const float* __restrict__ wo, ushort* __restrict__ xbf,
              ushort* __restrict__ wibf, ushort* __restrict__ wobf) {
    int idx = blockIdx.x * 256 + threadIdx.x;
    const float* src; ushort* dst; int shift, rel;
    if (idx < NCX)              { rel = idx;               src = x;  dst = xbf;  shift = 7; }
    else if (idx < NCX + NCWI)  { rel = idx - NCX;         src = wi; dst = wibf; shift = 7; }
    else                        { rel = idx - NCX - NCWI;  src = wo; dst = wobf; shift = 8; }
    int dc = rel ^ ((rel >> shift) & 7);
    const float* ip = src + (size_t)rel * 8;
    float4 v0 = *(const float4*)ip;
    float4 v1 = *(const float4*)(ip + 4);
    uint4 o;
    o.x = (unsigned)f2bf(v0.x) | ((unsigned)f2bf(v0.y) << 16);
    o.y = (unsigned)f2bf(v0.z) | ((unsigned)f2bf(v0.w) << 16);
    o.z = (unsigned)f2bf(v1.x) | ((unsigned)f2bf(v1.y) << 16);
    o.w = (unsigned)f2bf(v1.z) | ((unsigned)f2bf(v1.w) << 16);
    *(uint4*)(dst + (size_t)dc * 8) = o;
}

// ---------------------------------------------------------------------------
// bf16 MFMA GEMM NT (A,B pre-swizzled). 128x128 tile, BK=64, 4 waves 2x2.
// Supertile (4 by x SW bx) ordering, XCD chunk = one supertile row.
// Split output: cols < split -> bf16 Cb; else fp32 Cf. LDS-bounce epilogue.
// ---------------------------------------------------------------------------
__global__ __launch_bounds__(256, 2)
void gemm_bf16(const ushort* __restrict__ A, const ushort* __restrict__ B,
               float* __restrict__ Cf, ushort* __restrict__ Cb,
               int M, int N, int K, int split, int fstride, int SW) {
    __shared__ __align__(16) short lAB[2][128 * 64];
    short* lA = &lAB[0][0];
    short* lB = &lAB[1][0];
    int nwg = gridDim.x;
    int bid = blockIdx.x;
    int chunk = nwg >> 3;
    int swz = (bid & 7) * chunk + (bid >> 3);
    int nb = N >> 7;
    int sup = 4 * SW;
    int st = swz / sup, w = swz % sup;
    int stPerRow = nb / SW;
    int by = (st / stPerRow) * 4 + w / SW;
    int bx = (st % stPerRow) * SW + w % SW;

    int tid = threadIdx.x;
    int wv = tid >> 6, ln = tid & 63;
    int rl = ln & 15, kg = ln >> 4, r7 = rl & 7;
    int R0 = (wv >> 1) * 64, C0 = (wv & 1) * 64;

    const ushort* Ag = A + (size_t)(by * 128 + wv * 32 + (ln >> 3)) * K + (ln & 7) * 8;
    const ushort* Bg = B + (size_t)(bx * 128 + wv * 32 + (ln >> 3)) * K + (ln & 7) * 8;
    short* lAw = lA + (wv * 32) * 64;
    short* lBw = lB + (wv * 32) * 64;

    f4v acc[4][4];
#pragma unroll
    for (int m = 0; m < 4; ++m)
#pragma unroll
        for (int n = 0; n < 4; ++n) acc[m][n] = f4v{0.f, 0.f, 0.f, 0.f};

    for (int k0 = 0; k0 < K; k0 += 64) {
        __syncthreads();
#pragma unroll
        for (int i = 0; i < 4; ++i) {
            __builtin_amdgcn_global_load_lds(
                (const __attribute__((address_space(1))) void*)(Ag + (size_t)i * 8 * K + k0),
                (__attribute__((address_space(3))) void*)(lAw + i * 8 * 64), 16, 0, 0);
            __builtin_amdgcn_global_load_lds(
                (const __attribute__((address_space(1))) void*)(Bg + (size_t)i * 8 * K + k0),
                (__attribute__((address_space(3))) void*)(lBw + i * 8 * 64), 16, 0, 0);
        }
        __syncthreads();
#pragma unroll
        for (int ks = 0; ks < 2; ++ks) {
            int kc = ks * 4 + kg;
            int co = ((kc ^ r7) << 3);
            s8v av[4], bv[4];
#pragma unroll
            for (int m = 0; m < 4; ++m)
                av[m] = *(const s8v*)&lA[(R0 + m * 16 + rl) * 64 + co];
#pragma unroll
            for (int n = 0; n < 4; ++n)
                bv[n] = *(const s8v*)&lB[(C0 + n * 16 + rl) * 64 + co];
#pragma unroll
            for (int m = 0; m < 4; ++m)
#pragma unroll
                for (int n = 0; n < 4; ++n)
                    acc[m][n] = __builtin_amdgcn_mfma_f32_16x16x32_bf16(
                        av[m], bv[n], acc[m][n], 0, 0, 0);
        }
    }
    if (bx * 128 < split) {
        // bf16 output: bounce through LDS (128x128 ushort = 32KB)
        __syncthreads();
        ushort* ct = (ushort*)lAB;
#pragma unroll
        for (int m = 0; m < 4; ++m)
#pragma unroll
            for (int n = 0; n < 4; ++n)
#pragma unroll
                for (int r = 0; r < 4; ++r)
                    ct[(R0 + m * 16 + kg * 4 + r) * 128 + C0 + n * 16 + rl] =
                        f2bf(acc[m][n][r]);
        __syncthreads();
        ushort* cb = Cb + (size_t)(by * 128) * split + bx * 128;
        const uint4* cs = (const uint4*)ct;
#pragma unroll
        for (int k = 0; k < 8; ++k) {
            int idx = k * 256 + tid;
            int row = idx >> 4, cc = idx & 15;
            *(uint4*)(cb + (size_t)row * split + cc * 8) = cs[idx];
        }
    } else {
        // fp32 output: two column-half passes (128x64 f32 = 32KB each)
#pragma unroll
        for (int hp = 0; hp < 2; ++hp) {
            __syncthreads();
            float* cf = (float*)lAB;
            if ((wv & 1) == hp) {
#pragma unroll
                for (int m = 0; m < 4; ++m)
#pragma unroll
                    for (int n = 0; n < 4; ++n)
#pragma unroll
                        for (int r = 0; r < 4; ++r)
                            cf[(R0 + m * 16 + kg * 4 + r) * 64 + n * 16 + rl] =
                                acc[m][n][r];
            }
            __syncthreads();
            float* co = Cf + (size_t)(by * 128) * fstride + (bx * 128 - split) + hp * 64;
            const float4* fs = (const float4*)cf;
#pragma unroll
            for (int k = 0; k < 8; ++k) {
                int idx = k * 256 + tid;
                int row = idx >> 4, c4 = idx & 15;
                *(float4*)(co + (size_t)row * fstride + c4 * 4) = fs[idx];
            }
        }
    }
}

// ---------------------------------------------------------------------------
// Phase cumsum + cos/sin (angles from projS fp32).
// ---------------------------------------------------------------------------
__global__ __launch_bounds__(256)
void phase_kernel(const float* __restrict__ projS, float* __restrict__ cosb,
                  float* __restrict__ sinb) {
    int b = blockIdx.x >> 5;
    int j = blockIdx.x & 31;
    int tid = threadIdx.x;
    __shared__ float part[256];
    float v[8];
    float run = 0.f;
#pragma unroll
    for (int e = 0; e < 8; ++e) {
        int s = tid * 8 + e;
        v[e] = projS[((size_t)(b * S_LEN + s)) * PS + PS_ANG + j];
        run += v[e];
    }
    part[tid] = run;
    __syncthreads();
    for (int off = 1; off < 256; off <<= 1) {
        float add = (tid >= off) ? part[tid - off] : 0.f;
        __syncthreads();
        part[tid] += add;
        __syncthreads();
    }
    float acc = (tid > 0) ? part[tid - 1] : 0.f;
#pragma unroll
    for (int e = 0; e < 8; ++e) {
        acc += v[e];
        int s = tid * 8 + e;
        size_t o = ((size_t)(b * S_LEN + s)) * NA + j;
        cosb[o] = cosf(acc);
        sinb[o] = sinf(acc);
    }
}

// ---------------------------------------------------------------------------
// Slim per-(b,s,h) scalar prep: dt/A/trap -> ldb, wbuf, pubuf.
// grid = M*NH/256 = 512 blocks.
// ---------------------------------------------------------------------------
__global__ __launch_bounds__(256)
void sprep_kernel(const float* __restrict__ projS, const float* __restrict__ dt_bias,
                  float* __restrict__ ldb, float* __restrict__ wbuf,
                  float* __restrict__ pubuf) {
    int g = blockIdx.x * 256 + threadIdx.x;
    int row = g >> 5, h = g & 31;
    int b = row >> 11, s = row & 2047;
    const float* pr = projS + (size_t)row * PS;
    float dtv = softplus_f(pr[PS_DT + h] + dt_bias[h]);
    float Av = -fmaxf(softplus_f(pr[PS_A + h]), 1e-4f);
    float trap = 1.f / (1.f + expf(-pr[PS_TRAP + h]));
    size_t o = ((size_t)(b * NH + h)) * S_LEN + s;
    ldb[o]   = Av * dtv;
    wbuf[o]  = trap * dtv;
    pubuf[o] = (1.f - trap) * dtv;
}

// ---------------------------------------------------------------------------
// Inclusive cumsum of log-decay per (b,h) row.
// ---------------------------------------------------------------------------
__global__ __launch_bounds__(256)
void lcum_kernel(float* __restrict__ ell) {
    size_t row = blockIdx.x;
    int tid = threadIdx.x;
    float* p = ell + row * S_LEN;
    float v[8];
    float run = 0.f;
#pragma unroll
    for (int e = 0; e < 8; ++e) { v[e] = p[tid * 8 + e]; run += v[e]; }
    __shared__ float part[256];
    part[tid] = run;
    __syncthreads();
    for (int off = 1; off < 256; off <<= 1) {
        float add = (tid >= off) ? part[tid - off] : 0.f;
        __syncthreads();
        part[tid] += add;
        __syncthreads();
    }
    float acc = (tid > 0) ? part[tid - 1] : 0.f;
#pragma unroll
    for (int e = 0; e < 8; ++e) { acc += v[e]; p[tid * 8 + e] = acc; }
}

// ---------------------------------------------------------------------------
// Fused build of 32 values: RMSNorm(raw)*normw + bias, joint pair-rotation.
// The 4 threads of one row (lanes 4i..4i+3) cooperate on the row sumsq via
// __shfl_xor(1),(2). praw/nw/bias pre-offset to n0; cr/sr to this quarter.
// ---------------------------------------------------------------------------
__device__ __forceinline__ void buildnorm32(
    float* vals, const float* __restrict__ praw, const float* __restrict__ nw,
    const float* __restrict__ bias, const float* __restrict__ cr,
    const float* __restrict__ sr, int rot) {
    float bv[32], bi[32], nv[32];
#pragma unroll
    for (int j = 0; j < 8; ++j) *(float4*)&bv[j * 4] = *(const float4*)(praw + j * 4);
#pragma unroll
    for (int j = 0; j < 8; ++j) *(float4*)&bi[j * 4] = *(const float4*)(bias + j * 4);
#pragma unroll
    for (int j = 0; j < 8; ++j) *(float4*)&nv[j * 4] = *(const float4*)(nw + j * 4);
    float ss = 0.f;
#pragma unroll
    for (int j = 0; j < 32; ++j) ss += bv[j] * bv[j];
    ss += __shfl_xor(ss, 1);
    ss += __shfl_xor(ss, 2);
    float rinv = 1.f / sqrtf(ss * (1.f / 128.f) + 1e-5f);
    float tmp[32];
#pragma unroll
    for (int j = 0; j < 32; ++j) tmp[j] = bv[j] * rinv * nv[j] + bi[j];
    if (rot) {
        float cf[16], sf[16];
#pragma unroll
        for (int j = 0; j < 4; ++j) {
            *(float4*)&cf[j * 4] = *(const float4*)(cr + j * 4);
            *(float4*)&sf[j * 4] = *(const float4*)(sr + j * 4);
        }
#pragma unroll
        for (int a = 0; a < 16; ++a) {
            float c = cf[a], s = sf[a], e = tmp[2 * a], o = tmp[2 * a + 1];
            vals[2 * a]     = e * c - o * s;
            vals[2 * a + 1] = e * s + o * c;
        }
    } else {
#pragma unroll
        for (int j = 0; j < 32; ++j) vals[j] = tmp[j];
    }
}

// ---------------------------------------------------------------------------
// delta: Delta[p][n] -> bf16 swizzled to HBM (via LDS bounce, full-line).
// K built from raw projS (fused RMSNorm). Exports raw V^T + row-major K.
// grid 2048, 32KB LDS.
// ---------------------------------------------------------------------------
__global__ __launch_bounds__(256, 4)
void delta_kernel(const ushort* __restrict__ zvbf, const float* __restrict__ projS,
                  const float* __restrict__ Bw, const float* __restrict__ cosb,
                  const float* __restrict__ sinb, const float* __restrict__ ell,
                  const float* __restrict__ wbuf, const float* __restrict__ pubuf,
                  const float* __restrict__ B_bias, ushort* __restrict__ dstate,
                  ushort* __restrict__ vtbuf, ushort* __restrict__ kbuf,
                  float* __restrict__ rbuf) {
    __shared__ __align__(16) ushort KT[DS * CHK];   // [n][i] swz 16KB; then Delta
    __shared__ __align__(16) ushort cVT[HD * CHK];  // [p][i] swz 8KB
    __shared__ __align__(16) ushort VT[HD * CHK];   // raw [p][i] swz 8KB
    int blk = blockIdx.x;
    int c = blk & (NC - 1);
    int h = (blk >> 5) & (NH - 1);
    int b = blk >> 10;
    int tid = threadIdx.x;
    size_t row0 = (size_t)b * S_LEN + c * CHK;
    size_t bh = (size_t)b * NH + h;
    int i = tid >> 2, q4 = tid & 3;

    size_t so = bh * S_LEN + c * CHK + i;
    float llast = ell[bh * S_LEN + c * CHK + CHK - 1];
    float li = ell[so];
    float u = wbuf[so];
    if (c * CHK + i < S_LEN - 1) u += pubuf[so + 1];
    float coef = expf(llast - li) * u;   // llast <= li, no overflow
    if (tid == 0) {
        float base = (c == 0) ? 0.f : ell[bh * S_LEN + c * CHK - 1];
        rbuf[blk] = expf(llast - base);
    }
    {   // K build (fused rmsnorm): K^T to LDS + row-major K export
        int n0 = q4 * 32;
        float vals[32];
        buildnorm32(vals, projS + (row0 + i) * PS + PS_B + n0, Bw + n0,
                    B_bias + h * DS + n0,
                    cosb + (row0 + i) * NA + q4 * 16, sinb + (row0 + i) * NA + q4 * 16,
                    q4 < 2);
#pragma unroll
        for (int j = 0; j < 32; ++j) {
            int n = n0 + j;
            KT[n * 64 + (((i >> 3) ^ (n & 7)) << 3) + (i & 7)] = f2bf(vals[j]);
        }
        ushort* kd = kbuf + (size_t)blk * (CHK * DS);
#pragma unroll
        for (int j = 0; j < 4; ++j) {
            int cc = (q4 * 4 + j) ^ (i & 7);
            *(uint4*)&kd[i * 128 + cc * 8] = pack8(&vals[j * 8]);
        }
    }
    {   // V^T builds (raw + coef-scaled) from bf16 zvbf
        int p0 = q4 * 16;
        const ushort* vp = zvbf + (size_t)(row0 + i) * ZV + 2048 + h * HD + p0;
        uint4 a0 = *(const uint4*)vp;
        uint4 a1 = *(const uint4*)(vp + 8);
        unsigned uu[8] = {a0.x, a0.y, a0.z, a0.w, a1.x, a1.y, a1.z, a1.w};
#pragma unroll
        for (int j = 0; j < 8; ++j) {
            ushort v0 = (ushort)(uu[j] & 0xffffu);
            ushort v1 = (ushort)(uu[j] >> 16);
            int p = p0 + 2 * j;
            int addr0 = p * 64 + (((i >> 3) ^ (p & 7)) << 3) + (i & 7);
            int addr1 = (p + 1) * 64 + (((i >> 3) ^ ((p + 1) & 7)) << 3) + (i & 7);
            VT[addr0]  = v0;
            VT[addr1]  = v1;
            cVT[addr0] = f2bf(bf2f(v0) * coef);
            cVT[addr1] = f2bf(bf2f(v1) * coef);
        }
    }
    __syncthreads();
    // export raw VT (coalesced)
    {
        const uint4* vs = (const uint4*)VT;
        uint4* vd = (uint4*)(vtbuf + (size_t)blk * (HD * CHK));
        vd[tid] = vs[tid];
        vd[tid + 256] = vs[tid + 256];
    }
    int wv = tid >> 6, ln = tid & 63, rl = ln & 15, kg = ln >> 4;
    int pA = wv * 16 + rl;
    s8v aV[2];
#pragma unroll
    for (int ks = 0; ks < 2; ++ks)
        aV[ks] = *(const s8v*)&cVT[pA * 64 + (((ks * 4 + kg) ^ (pA & 7)) << 3)];
    f4v dacc[8];
    __builtin_amdgcn_s_setprio(1);
#pragma unroll
    for (int nt = 0; nt < 8; ++nt) {
        int nB = nt * 16 + rl;
        dacc[nt] = f4v{0.f, 0.f, 0.f, 0.f};
#pragma unroll
        for (int ks = 0; ks < 2; ++ks) {
            s8v bK = *(const s8v*)&KT[nB * 64 + (((ks * 4 + kg) ^ (nB & 7)) << 3)];
            dacc[nt] = __builtin_amdgcn_mfma_f32_16x16x32_bf16(aV[ks], bK, dacc[nt], 0, 0, 0);
        }
    }
    __builtin_amdgcn_s_setprio(0);
    __syncthreads();   // all KT reads done
    // bounce Delta through KT space (swizzled [p][n]), then coalesced export
#pragma unroll
    for (int nt = 0; nt < 8; ++nt) {
#pragma unroll
        for (int r = 0; r < 4; ++r) {
            int p = wv * 16 + kg * 4 + r;
            int n = nt * 16 + rl;
            KT[p * 128 + (((n >> 3) ^ (p & 7)) << 3) + (n & 7)] = f2bf(dacc[nt][r]);
        }
    }
    __syncthreads();
    {
        const uint4* dsr = (const uint4*)KT;
        uint4* dd = (uint4*)(dstate + (size_t)blk * (HD * DS));
#pragma unroll
        for (int k = 0; k < 4; ++k) dd[k * 256 + tid] = dsr[k * 256 + tid];
    }
}

// ---------------------------------------------------------------------------
// Chunk-state propagation, bf16 in/out, fp32 carry, in place on dstate.
// 4 n-slices per (b,h) -> 256 blocks. Each thread: one uint4 (8 elems)/chunk.
// ---------------------------------------------------------------------------
__global__ __launch_bounds__(256)
void state_prop(ushort* __restrict__ dstate, const float* __restrict__ rbuf) {
    int g = blockIdx.x;
    size_t bh = (size_t)(g >> 2);
    int sl = g & 3;
    int tid = threadIdx.x;
    float st[8];
#pragma unroll
    for (int j = 0; j < 8; ++j) st[j] = 0.f;
    uint4* base = (uint4*)dstate;
    size_t off0 = bh * NC * 1024ull + (size_t)sl * 256 + tid;
    uint4 nxt = base[off0];
    for (int c = 0; c < NC; ++c) {
        uint4 cur = nxt;
        if (c + 1 < NC) nxt = base[off0 + (size_t)(c + 1) * 1024];
        float r = rbuf[bh * NC + c];
        unsigned uu[4] = {cur.x, cur.y, cur.z, cur.w};
        unsigned oo[4];
#pragma unroll
        for (int e = 0; e < 4; ++e) {
            float d0 = bf_lo(uu[e]), d1 = bf_hi(uu[e]);
            int ix = e * 2;
            oo[e] = (unsigned)f2bf(st[ix]) | ((unsigned)f2bf(st[ix + 1]) << 16);
            st[ix]     = fmaf(r, st[ix], d0);
            st[ix + 1] = fmaf(r, st[ix + 1], d1);
        }
        base[off0 + (size_t)c * 1024] = uint4{oo[0], oo[1], oo[2], oo[3]};
    }
}

// ---------------------------------------------------------------------------
// out: K+VT staged via global_load_lds at start (hidden under Q build);
// Q built from raw projS (fused RMSNorm); P~=mask(QK^T);
// y = P~V + et*(Q S^T). 40KB LDS -> 4 blocks/CU.
// ---------------------------------------------------------------------------
__global__ __launch_bounds__(256, 4)
void out_kernel(const float* __restrict__ projS, const float* __restrict__ Cw,
                const float* __restrict__ cosb, const float* __restrict__ sinb,
                const float* __restrict__ ell, const float* __restrict__ wbuf,
                const float* __restrict__ pubuf, const float* __restrict__ C_bias,
                const ushort* __restrict__ dstate, const ushort* __restrict__ vtbuf,
                const ushort* __restrict__ kbuf, float* __restrict__ yb) {
    __shared__ __align__(16) ushort Qb[CHK * DS];    // 16KB: Q; then PTb; then y-tile
    __shared__ __align__(16) ushort Kb[CHK * DS];    // 16KB: K staged, then S
    __shared__ __align__(16) ushort VTb[HD * CHK];   // 8KB: V^T [p][t]
    int blk = blockIdx.x;
    int c = blk & (NC - 1);
    int h = (blk >> 5) & (NH - 1);
    int b = blk >> 10;
    int tid = threadIdx.x;
    size_t row0 = (size_t)b * S_LEN + c * CHK;
    size_t bh = (size_t)b * NH + h;
    int i = tid >> 2, q4 = tid & 3;
    int wv2 = tid >> 6, ln = tid & 63;

    // stage K and VT immediately (lands under the Q build)
    {
        const ushort* kg_ = kbuf + (size_t)blk * (CHK * DS);
#pragma unroll
        for (int k = 0; k < 4; ++k) {
            int ch = wv2 * 256 + k * 64;
            __builtin_amdgcn_global_load_lds(
                (const __attribute__((address_space(1))) void*)(kg_ + (size_t)(ch + ln) * 8),
                (__attribute__((address_space(3))) void*)(Kb + ch * 8), 16, 0, 0);
        }
        const ushort* vg = vtbuf + (size_t)blk * (HD * CHK);
#pragma unroll
        for (int k = 0; k < 2; ++k) {
            int ch = wv2 * 128 + k * 64;
            __builtin_amdgcn_global_load_lds(
                (const __attribute__((address_space(1))) void*)(vg + (size_t)(ch + ln) * 8),
                (__attribute__((address_space(3))) void*)(VTb + ch * 8), 16, 0, 0);
        }
    }
    {   // Q build (fused rmsnorm)
        int n0 = q4 * 32;
        float vals[32];
        buildnorm32(vals, projS + (row0 + i) * PS + PS_C + n0, Cw + n0,
                    C_bias + h * DS + n0,
                    cosb + (row0 + i) * NA + q4 * 16, sinb + (row0 + i) * NA + q4 * 16,
                    q4 < 2);
#pragma unroll
        for (int j = 0; j < 4; ++j) {
            int cc = (q4 * 4 + j) ^ (i & 7);
            *(uint4*)&Qb[i * 128 + cc * 8] = pack8(&vals[j * 8]);
        }
    }
    __syncthreads();   // drains K/VT DMA + Q visible

    int rl = ln & 15, kg = ln >> 4;
    int tA = wv2 * 16 + rl;
    s8v aQ[4];
#pragma unroll
    for (int kc = 0; kc < 4; ++kc)
        aQ[kc] = *(const s8v*)&Qb[tA * 128 + (((kc * 4 + kg) ^ (tA & 7)) << 3)];
    f4v pacc[4];
#pragma unroll
    for (int st = 0; st < 4; ++st) pacc[st] = f4v{0.f, 0.f, 0.f, 0.f};
    __builtin_amdgcn_s_setprio(1);
#pragma unroll
    for (int st = 0; st < 4; ++st) {
        int sB = st * 16 + rl;
#pragma unroll
        for (int kc = 0; kc < 4; ++kc) {
            s8v bK = *(const s8v*)&Kb[sB * 128 + (((kc * 4 + kg) ^ (sB & 7)) << 3)];
            pacc[st] = __builtin_amdgcn_mfma_f32_16x16x32_bf16(aQ[kc], bK, pacc[st], 0, 0, 0);
        }
    }
    __builtin_amdgcn_s_setprio(0);
    __syncthreads();   // Kb and Qb free (aQ in regs)

    // issue S load into Kb space (overlaps with mask phase)
    {
        const ushort* sg = dstate + (size_t)blk * (CHK * DS);
#pragma unroll
        for (int k = 0; k < 4; ++k) {
            int ch = wv2 * 256 + k * 64;
            __builtin_amdgcn_global_load_lds(
                (const __attribute__((address_space(1))) void*)(sg + (size_t)(ch + ln) * 8),
                (__attribute__((address_space(3))) void*)(Kb + ch * 8), 16, 0, 0);
        }
    }
    // recompute mask scalars (L2-hot reads, no LDS)
    size_t so0 = bh * S_LEN + c * CHK;
    float basev = (c == 0) ? 0.f : ell[so0 - 1];
    int t2r0 = wv2 * 16 + kg * 4;
    float et[4], wr[4];
#pragma unroll
    for (int r = 0; r < 4; ++r) {
        size_t so = so0 + t2r0 + r;
        et[r] = expf(ell[so] - basev);
        wr[r] = wbuf[so];
    }
    float fs[4];
#pragma unroll
    for (int st = 0; st < 4; ++st) {
        int s = st * 16 + rl;
        size_t sos = so0 + s;
        float u = wbuf[sos];
        if (c * CHK + s < S_LEN - 1) u += pubuf[sos + 1];
        fs[st] = u * expf(fminf(basev - ell[sos], 80.f));
    }
    // mask + pack P~ [t][s] into PTb (= Qb first 8KB)
    ushort* PTb = Qb;
#pragma unroll
    for (int st = 0; st < 4; ++st) {
        int s = st * 16 + rl;
#pragma unroll
        for (int r = 0; r < 4; ++r) {
            int t2 = t2r0 + r;
            float m;
            if (s < t2)       m = et[r] * fs[st];
            else if (s == t2) m = wr[r];
            else              m = 0.f;
            PTb[t2 * 64 + (((s >> 3) ^ (t2 & 7)) << 3) + (s & 7)] = f2bf(pacc[st][r] * m);
        }
    }
    __syncthreads();   // drains S DMA + PTb visible

    s8v aP[2];
#pragma unroll
    for (int ks = 0; ks < 2; ++ks)
        aP[ks] = *(const s8v*)&PTb[tA * 64 + (((ks * 4 + kg) ^ (tA & 7)) << 3)];
    f4v y1[4], y2[4];
#pragma unroll
    for (int pt = 0; pt < 4; ++pt) { y1[pt] = f4v{0.f,0.f,0.f,0.f}; y2[pt] = f4v{0.f,0.f,0.f,0.f}; }
    __builtin_amdgcn_s_setprio(1);
#pragma unroll
    for (int pt = 0; pt < 4; ++pt) {
        int pB = pt * 16 + rl;
#pragma unroll
        for (int ks = 0; ks < 2; ++ks) {
            s8v bV = *(const s8v*)&VTb[pB * 64 + (((ks * 4 + kg) ^ (pB & 7)) << 3)];
            y1[pt] = __builtin_amdgcn_mfma_f32_16x16x32_bf16(aP[ks], bV, y1[pt], 0, 0, 0);
        }
#pragma unroll
        for (int kc = 0; kc < 4; ++kc) {
            s8v bS = *(const s8v*)&Kb[pB * 128 + (((kc * 4 + kg) ^ (pB & 7)) << 3)];
            y2[pt] = __builtin_amdgcn_mfma_f32_16x16x32_bf16(aQ[kc], bS, y2[pt], 0, 0, 0);
        }
    }
    __builtin_amdgcn_s_setprio(0);
    // bounce y tile through Qb (64x64 f32 = 16KB), then coalesced write
    __syncthreads();   // all LDS reads done
    float* ct = (float*)Qb;
#pragma unroll
    for (int pt = 0; pt < 4; ++pt) {
#pragma unroll
        for (int r = 0; r < 4; ++r) {
            int t2 = t2r0 + r;
            int p = pt * 16 + rl;
            ct[t2 * 64 + p] = y1[pt][r] + et[r] * y2[pt][r];
        }
    }
    __syncthreads();
    {
        float* yp = yb + (size_t)blk * (CHK * HD);
        const float4* fsrc = (const float4*)ct;
#pragma unroll
        for (int k = 0; k < 4; ++k) {
            int idx = k * 256 + tid;
            *(float4*)(yp + idx * 4) = fsrc[idx];
        }
    }
}

// ---------------------------------------------------------------------------
// ynorm: y = yb(blocked) + D*v; rmsnorm * w * silu(z) -> bf16 swizzled.
// ---------------------------------------------------------------------------
__global__ __launch_bounds__(256)
void ynorm_kernel(const float* __restrict__ yb, const ushort* __restrict__ zvbf,
                  const float* __restrict__ w, const float* __restrict__ D_param,
                  ushort* __restrict__ ybf) {
    size_t row = blockIdx.x;
    int b = (int)(row >> 11);
    int s = (int)(row & 2047);
    int c = s >> 6, t = s & 63;
    int tid = threadIdx.x;
    int hh = tid >> 3;                 // head for this thread's 8 cols
    int p0 = (tid * 8) & 63;
    const float* yr = yb + (((size_t)(b * NH + hh) * NC + c) * CHK + t) * HD + p0;
    float4 v0 = *(const float4*)yr;
    float4 v1 = *(const float4*)(yr + 4);
    float vvf[8];
    unpack8(*(const uint4*)(zvbf + row * (size_t)ZV + 2048 + tid * 8), vvf);
    float Dp = D_param[hh];
    float yv[8] = {v0.x + Dp * vvf[0], v0.y + Dp * vvf[1], v0.z + Dp * vvf[2], v0.w + Dp * vvf[3],
                   v1.x + Dp * vvf[4], v1.y + Dp * vvf[5], v1.z + Dp * vvf[6], v1.w + Dp * vvf[7]};
    float ss = 0.f;
#pragma unroll
    for (int e = 0; e < 8; ++e) ss += yv[e] * yv[e];
#pragma unroll
    for (int off = 32; off >= 1; off >>= 1) ss += __shfl_xor(ss, off);
    __shared__ float red[4];
    if ((tid & 63) == 0) red[tid >> 6] = ss;
    __syncthreads();
    float tot = red[0] + red[1] + red[2] + red[3];
    float rinv = 1.f / sqrtf(tot * (1.f / 2048.f) + 1e-5f);
    float zv[8];
    unpack8(*(const uint4*)(zvbf + row * (size_t)ZV + tid * 8), zv);
    float4 w0 = *(const float4*)(w + tid * 8);
    float4 w1 = *(const float4*)(w + tid * 8 + 4);
    float wv[8] = {w0.x, w0.y, w0.z, w0.w, w1.x, w1.y, w1.z, w1.w};
    ushort u[8];
#pragma unroll
    for (int e = 0; e < 8; ++e) {
        float sil = zv[e] / (1.f + expf(-zv[e]));
        u[e] = f2bf(yv[e] * rinv * wv[e] * sil);
    }
    int dstc = (tid & ~7) | ((tid & 7) ^ ((int)row & 7));
    uint4 o;
    o.x = (unsigned)u[0] | ((unsigned)u[1] << 16);
    o.y = (unsigned)u[2] | ((unsigned)u[3] << 16);
    o.z = (unsigned)u[4] | ((unsigned)u[5] << 16);
    o.w = (unsigned)u[6] | ((unsigned)u[7] << 16);
    *(uint4*)(ybf + row * (size_t)DI + dstc * 8) = o;
}

// ---------------------------------------------------------------------------
extern "C" void kernel_launch(void* const* d_in, const int* in_sizes, int n_in,
                              void* d_out, int out_size, void* d_ws, size_t ws_size,
                              hipStream_t stream) {
    const float* x          = (const float*)d_in[0];
    const float* W_in       = (const float*)d_in[1];
    const float* dt_bias    = (const float*)d_in[2];
    const float* B_norm_w   = (const float*)d_in[3];
    const float* C_norm_w   = (const float*)d_in[4];
    const float* B_bias     = (const float*)d_in[5];
    const float* C_bias     = (const float*)d_in[6];
    const float* D_param    = (const float*)d_in[7];
    const float* out_norm_w = (const float*)d_in[8];
    const float* W_out      = (const float*)d_in[9];
    float* out = (float*)d_out;

    const size_t M = (size_t)NBATCH * S_LEN;       // 4096
    const size_t NBLK = (size_t)NBATCH * NH * NC;  // 2048
    float* ws = (float*)d_ws;
    size_t off = 0;
    float* projS = ws + off; off += M * PS;            // fp32 scalar cols
    float* cosb  = ws + off; off += M * NA;
    float* sinb  = ws + off; off += M * NA;
    float* ell   = ws + off; off += (size_t)NBATCH * NH * S_LEN;
    float* wbuf  = ws + off; off += (size_t)NBATCH * NH * S_LEN;
    float* pubuf = ws + off; off += (size_t)NBATCH * NH * S_LEN;
    float* yb    = ws + off; off += NBLK * CHK * HD;   // blocked y_partial
    float* rbuf  = ws + off; off += NBLK;
    ushort* zvbf = (ushort*)(ws + off); off += M * ZV / 2;   // z|v bf16
    ushort* xbf  = (ushort*)(ws + off); off += M * DMODEL / 2;
    ushort* wibf = (ushort*)(ws + off); off += (size_t)PDIM * DMODEL / 2;
    ushort* wobf = (ushort*)(ws + off); off += (size_t)DMODEL * DI / 2;
    ushort* ybf  = (ushort*)(ws + off); off += M * DI / 2;
    ushort* dstate = (ushort*)(ws + off); off += NBLK * CHK * DS / 2;
    ushort* vtbuf  = (ushort*)(ws + off); off += NBLK * HD * CHK / 2;
    ushort* kbuf   = (ushort*)(ws + off); off += NBLK * CHK * DS / 2;

    // 0) fused fp32 -> bf16 (swizzled) conversions
    f2bf_all<<<dim3((NCX + NCWI + NCWO) / 256), 256, 0, stream>>>(
        x, W_in, W_out, xbf, wibf, wobf);
    // 1) proj = x @ W_in^T : cols<4096 -> zvbf bf16, cols>=4096 -> projS fp32
    gemm_bf16<<<dim3((PDIM / 128) * (int)(M / 128)), 256, 0, stream>>>(
        xbf, wibf, projS, zvbf, (int)M, PDIM, DMODEL, ZV, PS, 5);
    // 2) phase cumsum -> cos/sin
    phase_kernel<<<dim3(NBATCH * NA), 256, 0, stream>>>(projS, cosb, sinb);
    // 3) slim scalar prep (dt/A/trap)
    sprep_kernel<<<dim3((int)(M * NH / 256)), 256, 0, stream>>>(projS, dt_bias,
                                                                ell, wbuf, pubuf);
    // 4) cumsum of log-decay
    lcum_kernel<<<dim3(NBATCH * NH), 256, 0, stream>>>(ell);
    // 5) per-chunk delta states + VT/K export (fused B rmsnorm)
    delta_kernel<<<dim3((int)NBLK), 256, 0, stream>>>(zvbf, projS, B_norm_w,
                                                      cosb, sinb, ell,
                                                      wbuf, pubuf, B_bias, dstate,
                                                      vtbuf, kbuf, rbuf);
    // 6) chunk-state propagation (bf16, in place, 4 slices/bh)
    state_prop<<<dim3(NBATCH * NH * 4), 256, 0, stream>>>(dstate, rbuf);
    // 7) per-chunk outputs (staged K/VT/S, fused C rmsnorm Q-build)
    out_kernel<<<dim3((int)NBLK), 256, 0, stream>>>(projS, C_norm_w, cosb, sinb,
                                                    ell, wbuf, pubuf, C_bias,
                                                    dstate, vtbuf, kbuf, yb);
    // 8) y = rmsnorm(yb + D*v)*w*silu(z) -> bf16 swizzled
    ynorm_kernel<<<dim3((int)M), 256, 0, stream>>>(yb, zvbf, out_norm_w, D_param, ybf);
    // 9) out = y @ W_out^T (all fp32 out)
    gemm_bf16<<<dim3((DMODEL / 128) * (int)(M / 128)), 256, 0, stream>>>(
        ybf, wobf, out, nullptr, (int)M, DMODEL, DI, 0, DMODEL, 4);
}

// Round 17
// 216.176 us; speedup vs baseline: 1.0412x; 1.0412x over previous
//
#include <hip/hip_runtime.h>
#include <math.h>

#define S_LEN 2048
#define NBATCH 2
#define DMODEL 1024
#define PDIM 4480   // 2*2048 + 2*128 + 3*32 + 32
#define DI 2048
#define NH 32
#define HD 64
#define DS 128
#define NA 32
#define CHK 64
#define NC (S_LEN / CHK)   // 32 chunks per batch
#define ZV 4096            // z|v bf16 columns
#define PS 384             // fp32 scalar columns (B,C,dt,A,trap,ang)
// projS column offsets (proj col - 4096)
#define PS_B 0
#define PS_C 128
#define PS_DT 256
#define PS_A 288
#define PS_TRAP 320
#define PS_ANG 352

typedef __attribute__((ext_vector_type(8))) short s8v;
typedef __attribute__((ext_vector_type(4))) float f4v;

__device__ __forceinline__ float softplus_f(float x) {
    return x > 20.f ? x : log1pf(expf(x));
}

__device__ __forceinline__ ushort f2bf(float f) {
    unsigned u = __float_as_uint(f);
    unsigned r = (u + 0x7fffu + ((u >> 16) & 1u)) >> 16;
    return (ushort)r;
}

__device__ __forceinline__ uint4 pack8(const float* f) {
    uint4 o;
    o.x = (unsigned)f2bf(f[0]) | ((unsigned)f2bf(f[1]) << 16);
    o.y = (unsigned)f2bf(f[2]) | ((unsigned)f2bf(f[3]) << 16);
    o.z = (unsigned)f2bf(f[4]) | ((unsigned)f2bf(f[5]) << 16);
    o.w = (unsigned)f2bf(f[6]) | ((unsigned)f2bf(f[7]) << 16);
    return o;
}

__device__ __forceinline__ float bf2f(ushort u) {
    return __uint_as_float(((unsigned)u) << 16);
}
__device__ __forceinline__ float bf_lo(unsigned u) { return __uint_as_float(u << 16); }
__device__ __forceinline__ float bf_hi(unsigned u) { return __uint_as_float(u & 0xffff0000u); }

__device__ __forceinline__ void unpack8(uint4 a, float* f) {
    f[0] = bf_lo(a.x); f[1] = bf_hi(a.x);
    f[2] = bf_lo(a.y); f[3] = bf_hi(a.y);
    f[4] = bf_lo(a.z); f[5] = bf_hi(a.z);
    f[6] = bf_lo(a.w); f[7] = bf_hi(a.w);
}

// ---------------------------------------------------------------------------
// Fused fp32 -> bf16 swizzled conversion for x, W_in, W_out (one launch).
// ---------------------------------------------------------------------------
#define NCX  524288   // 4096*1024/8
#define NCWI 573440   // 4480*1024/8
#define NCWO 262144   // 2048*1024/8
__global__ __launch_bounds__(256)
void f2bf_all(const float* __restrict__ x, const float* __restrict__ wi,
              const float* __restrict__ wo, ushort* __restrict__ xbf,
              ushort* __restrict__ wibf, ushort* __restrict__ wobf) {
    int idx = blockIdx.x * 256 + threadIdx.x;
    const float* src; ushort* dst; int shift, rel;
    if (idx < NCX)              { rel = idx;               src = x;  dst = xbf;  shift = 7; }
    else if (idx < NCX + NCWI)  { rel = idx - NCX;         src = wi; dst = wibf; shift = 7; }
    else                        { rel = idx - NCX - NCWI;  src = wo; dst = wobf; shift = 8; }
    int dc = rel ^ ((rel >> shift) & 7);
    const float* ip = src + (size_t)rel * 8;
    float4 v0 = *(const float4*)ip;
    float4 v1 = *(const float4*)(ip + 4);
    uint4 o;
    o.x = (unsigned)f2bf(v0.x) | ((unsigned)f2bf(v0.y) << 16);
    o.y = (unsigned)f2bf(v0.z) | ((unsigned)f2bf(v0.w) << 16);
    o.z = (unsigned)f2bf(v1.x) | ((unsigned)f2bf(v1.y) << 16);
    o.w = (unsigned)f2bf(v1.z) | ((unsigned)f2bf(v1.w) << 16);
    *(uint4*)(dst + (size_t)dc * 8) = o;
}

// ---------------------------------------------------------------------------
// bf16 MFMA GEMM NT (A,B pre-swizzled). 128x128 tile, BK=64, 4 waves 2x2.
// Supertile (4 by x SW bx) ordering, XCD chunk = one supertile row.
// Split output: cols < split -> bf16 Cb; else fp32 Cf. LDS-bounce epilogue.
// ---------------------------------------------------------------------------
__global__ __launch_bounds__(256, 2)
void gemm_bf16(const ushort* __restrict__ A, const ushort* __restrict__ B,
               float* __restrict__ Cf, ushort* __restrict__ Cb,
               int M, int N, int K, int split, int fstride, int SW) {
    __shared__ __align__(16) short lAB[2][128 * 64];
    short* lA = &lAB[0][0];
    short* lB = &lAB[1][0];
    int nwg = gridDim.x;
    int bid = blockIdx.x;
    int chunk = nwg >> 3;
    int swz = (bid & 7) * chunk + (bid >> 3);
    int nb = N >> 7;
    int sup = 4 * SW;
    int st = swz / sup, w = swz % sup;
    int stPerRow = nb / SW;
    int by = (st / stPerRow) * 4 + w / SW;
    int bx = (st % stPerRow) * SW + w % SW;

    int tid = threadIdx.x;
    int wv = tid >> 6, ln = tid & 63;
    int rl = ln & 15, kg = ln >> 4, r7 = rl & 7;
    int R0 = (wv >> 1) * 64, C0 = (wv & 1) * 64;

    const ushort* Ag = A + (size_t)(by * 128 + wv * 32 + (ln >> 3)) * K + (ln & 7) * 8;
    const ushort* Bg = B + (size_t)(bx * 128 + wv * 32 + (ln >> 3)) * K + (ln & 7) * 8;
    short* lAw = lA + (wv * 32) * 64;
    short* lBw = lB + (wv * 32) * 64;

    f4v acc[4][4];
#pragma unroll
    for (int m = 0; m < 4; ++m)
#pragma unroll
        for (int n = 0; n < 4; ++n) acc[m][n] = f4v{0.f, 0.f, 0.f, 0.f};

    for (int k0 = 0; k0 < K; k0 += 64) {
        __syncthreads();
#pragma unroll
        for (int i = 0; i < 4; ++i) {
            __builtin_amdgcn_global_load_lds(
                (const __attribute__((address_space(1))) void*)(Ag + (size_t)i * 8 * K + k0),
                (__attribute__((address_space(3))) void*)(lAw + i * 8 * 64), 16, 0, 0);
            __builtin_amdgcn_global_load_lds(
                (const __attribute__((address_space(1))) void*)(Bg + (size_t)i * 8 * K + k0),
                (__attribute__((address_space(3))) void*)(lBw + i * 8 * 64), 16, 0, 0);
        }
        __syncthreads();
#pragma unroll
        for (int ks = 0; ks < 2; ++ks) {
            int kc = ks * 4 + kg;
            int co = ((kc ^ r7) << 3);
            s8v av[4], bv[4];
#pragma unroll
            for (int m = 0; m < 4; ++m)
                av[m] = *(const s8v*)&lA[(R0 + m * 16 + rl) * 64 + co];
#pragma unroll
            for (int n = 0; n < 4; ++n)
                bv[n] = *(const s8v*)&lB[(C0 + n * 16 + rl) * 64 + co];
#pragma unroll
            for (int m = 0; m < 4; ++m)
#pragma unroll
                for (int n = 0; n < 4; ++n)
                    acc[m][n] = __builtin_amdgcn_mfma_f32_16x16x32_bf16(
                        av[m], bv[n], acc[m][n], 0, 0, 0);
        }
    }
    if (bx * 128 < split) {
        // bf16 output: bounce through LDS (128x128 ushort = 32KB)
        __syncthreads();
        ushort* ct = (ushort*)lAB;
#pragma unroll
        for (int m = 0; m < 4; ++m)
#pragma unroll
            for (int n = 0; n < 4; ++n)
#pragma unroll
                for (int r = 0; r < 4; ++r)
                    ct[(R0 + m * 16 + kg * 4 + r) * 128 + C0 + n * 16 + rl] =
                        f2bf(acc[m][n][r]);
        __syncthreads();
        ushort* cb = Cb + (size_t)(by * 128) * split + bx * 128;
        const uint4* cs = (const uint4*)ct;
#pragma unroll
        for (int k = 0; k < 8; ++k) {
            int idx = k * 256 + tid;
            int row = idx >> 4, cc = idx & 15;
            *(uint4*)(cb + (size_t)row * split + cc * 8) = cs[idx];
        }
    } else {
        // fp32 output: two column-half passes (128x64 f32 = 32KB each)
#pragma unroll
        for (int hp = 0; hp < 2; ++hp) {
            __syncthreads();
            float* cf = (float*)lAB;
            if ((wv & 1) == hp) {
#pragma unroll
                for (int m = 0; m < 4; ++m)
#pragma unroll
                    for (int n = 0; n < 4; ++n)
#pragma unroll
                        for (int r = 0; r < 4; ++r)
                            cf[(R0 + m * 16 + kg * 4 + r) * 64 + n * 16 + rl] =
                                acc[m][n][r];
            }
            __syncthreads();
            float* co = Cf + (size_t)(by * 128) * fstride + (bx * 128 - split) + hp * 64;
            const float4* fs = (const float4*)cf;
#pragma unroll
            for (int k = 0; k < 8; ++k) {
                int idx = k * 256 + tid;
                int row = idx >> 4, c4 = idx & 15;
                *(float4*)(co + (size_t)row * fstride + c4 * 4) = fs[idx];
            }
        }
    }
}

// ---------------------------------------------------------------------------
// Phase cumsum + cos/sin (angles from projS fp32).
// ---------------------------------------------------------------------------
__global__ __launch_bounds__(256)
void phase_kernel(const float* __restrict__ projS, float* __restrict__ cosb,
                  float* __restrict__ sinb) {
    int b = blockIdx.x >> 5;
    int j = blockIdx.x & 31;
    int tid = threadIdx.x;
    __shared__ float part[256];
    float v[8];
    float run = 0.f;
#pragma unroll
    for (int e = 0; e < 8; ++e) {
        int s = tid * 8 + e;
        v[e] = projS[((size_t)(b * S_LEN + s)) * PS + PS_ANG + j];
        run += v[e];
    }
    part[tid] = run;
    __syncthreads();
    for (int off = 1; off < 256; off <<= 1) {
        float add = (tid >= off) ? part[tid - off] : 0.f;
        __syncthreads();
        part[tid] += add;
        __syncthreads();
    }
    float acc = (tid > 0) ? part[tid - 1] : 0.f;
#pragma unroll
    for (int e = 0; e < 8; ++e) {
        acc += v[e];
        int s = tid * 8 + e;
        size_t o = ((size_t)(b * S_LEN + s)) * NA + j;
        cosb[o] = cosf(acc);
        sinb[o] = sinf(acc);
    }
}

// ---------------------------------------------------------------------------
// Per-(b,s) prep: RMSNorm B/C (rotate norm part), per-head scalars.
// ---------------------------------------------------------------------------
__global__ __launch_bounds__(128)
void prep_kernel(const float* __restrict__ projS, const float* __restrict__ dt_bias,
                 const float* __restrict__ Bw, const float* __restrict__ Cw,
                 const float* __restrict__ cosb, const float* __restrict__ sinb,
                 float* __restrict__ Bn, float* __restrict__ Cn,
                 float* __restrict__ ldb, float* __restrict__ wbuf,
                 float* __restrict__ pubuf) {
    size_t row = blockIdx.x;
    int b = (int)(row >> 11);
    int s = (int)(row & 2047);
    int n = threadIdx.x;
    const float* pr = projS + row * PS;
    float vB = pr[PS_B + n];
    float vC = pr[PS_C + n];
    float sB = vB * vB, sC = vC * vC;
#pragma unroll
    for (int off = 32; off >= 1; off >>= 1) {
        sB += __shfl_xor(sB, off);
        sC += __shfl_xor(sC, off);
    }
    __shared__ float redB[2], redC[2];
    if ((n & 63) == 0) { redB[n >> 6] = sB; redC[n >> 6] = sC; }
    __syncthreads();
    float rB = sqrtf((redB[0] + redB[1]) * (1.f / 128.f) + 1e-5f);
    float rC = sqrtf((redC[0] + redC[1]) * (1.f / 128.f) + 1e-5f);
    float bn = vB / rB * Bw[n];
    float cn = vC / rC * Cw[n];
    float bp = __shfl_xor(bn, 1);
    float cp = __shfl_xor(cn, 1);
    float ob = bn, oc = cn;
    if (n < 64) {
        float c = cosb[row * NA + (n >> 1)];
        float sn_ = sinb[row * NA + (n >> 1)];
        if ((n & 1) == 0) { ob = bn * c - bp * sn_; oc = cn * c - cp * sn_; }
        else              { ob = bp * sn_ + bn * c; oc = cp * sn_ + cn * c; }
    }
    Bn[row * DS + n] = ob;
    Cn[row * DS + n] = oc;
    if (n < NH) {
        int h = n;
        float dtv = softplus_f(pr[PS_DT + h] + dt_bias[h]);
        float Av = -fmaxf(softplus_f(pr[PS_A + h]), 1e-4f);
        float trap = 1.f / (1.f + expf(-pr[PS_TRAP + h]));
        size_t o = ((size_t)(b * NH + h)) * S_LEN + s;
        ldb[o]   = Av * dtv;
        wbuf[o]  = trap * dtv;
        pubuf[o] = (1.f - trap) * dtv;
    }
}

// ---------------------------------------------------------------------------
// Inclusive cumsum of log-decay per (b,h) row.
// ---------------------------------------------------------------------------
__global__ __launch_bounds__(256)
void lcum_kernel(float* __restrict__ ell) {
    size_t row = blockIdx.x;
    int tid = threadIdx.x;
    float* p = ell + row * S_LEN;
    float v[8];
    float run = 0.f;
#pragma unroll
    for (int e = 0; e < 8; ++e) { v[e] = p[tid * 8 + e]; run += v[e]; }
    __shared__ float part[256];
    part[tid] = run;
    __syncthreads();
    for (int off = 1; off < 256; off <<= 1) {
        float add = (tid >= off) ? part[tid - off] : 0.f;
        __syncthreads();
        part[tid] += add;
        __syncthreads();
    }
    float acc = (tid > 0) ? part[tid - 1] : 0.f;
#pragma unroll
    for (int e = 0; e < 8; ++e) { acc += v[e]; p[tid * 8 + e] = acc; }
}

// ---------------------------------------------------------------------------
// Vectorized build of 32 rotated values (base + rot(bias)).
// ---------------------------------------------------------------------------
__device__ __forceinline__ void build32v(
    float* vals, const float* __restrict__ br, const float* __restrict__ bias,
    const float* __restrict__ cr, const float* __restrict__ sr, int rot) {
    float bv[32], bi[32];
#pragma unroll
    for (int j = 0; j < 8; ++j) *(float4*)&bv[j * 4] = *(const float4*)(br + j * 4);
#pragma unroll
    for (int j = 0; j < 8; ++j) *(float4*)&bi[j * 4] = *(const float4*)(bias + j * 4);
    if (rot) {
        float cf[16], sf[16];
#pragma unroll
        for (int j = 0; j < 4; ++j) {
            *(float4*)&cf[j * 4] = *(const float4*)(cr + j * 4);
            *(float4*)&sf[j * 4] = *(const float4*)(sr + j * 4);
        }
#pragma unroll
        for (int a = 0; a < 16; ++a) {
            float c = cf[a], s = sf[a], e = bi[2 * a], o = bi[2 * a + 1];
            vals[2 * a]     = bv[2 * a]     + e * c - o * s;
            vals[2 * a + 1] = bv[2 * a + 1] + e * s + o * c;
        }
    } else {
#pragma unroll
        for (int j = 0; j < 32; ++j) vals[j] = bv[j] + bi[j];
    }
}

// ---------------------------------------------------------------------------
// delta: Delta[p][n] -> bf16 swizzled to HBM (via LDS bounce, full-line).
// Also exports raw V^T tile and row-major K tile. grid 2048, 32KB LDS.
// ---------------------------------------------------------------------------
__global__ __launch_bounds__(256, 4)
void delta_kernel(const ushort* __restrict__ zvbf, const float* __restrict__ Bn,
                  const float* __restrict__ cosb, const float* __restrict__ sinb,
                  const float* __restrict__ ell, const float* __restrict__ wbuf,
                  const float* __restrict__ pubuf, const float* __restrict__ B_bias,
                  ushort* __restrict__ dstate, ushort* __restrict__ vtbuf,
                  ushort* __restrict__ kbuf, float* __restrict__ rbuf) {
    __shared__ __align__(16) ushort KT[DS * CHK];   // [n][i] swz 16KB; then Delta
    __shared__ __align__(16) ushort cVT[HD * CHK];  // [p][i] swz 8KB
    __shared__ __align__(16) ushort VT[HD * CHK];   // raw [p][i] swz 8KB
    int blk = blockIdx.x;
    int c = blk & (NC - 1);
    int h = (blk >> 5) & (NH - 1);
    int b = blk >> 10;
    int tid = threadIdx.x;
    size_t row0 = (size_t)b * S_LEN + c * CHK;
    size_t bh = (size_t)b * NH + h;
    int i = tid >> 2, q4 = tid & 3;

    size_t so = bh * S_LEN + c * CHK + i;
    float llast = ell[bh * S_LEN + c * CHK + CHK - 1];
    float li = ell[so];
    float u = wbuf[so];
    if (c * CHK + i < S_LEN - 1) u += pubuf[so + 1];
    float coef = expf(llast - li) * u;   // llast <= li, no overflow
    if (tid == 0) {
        float base = (c == 0) ? 0.f : ell[bh * S_LEN + c * CHK - 1];
        rbuf[blk] = expf(llast - base);
    }
    {   // K build: K^T to LDS + row-major K export (values already in regs)
        int n0 = q4 * 32;
        float vals[32];
        build32v(vals, Bn + (row0 + i) * DS + n0, B_bias + h * DS + n0,
                 cosb + (row0 + i) * NA + q4 * 16, sinb + (row0 + i) * NA + q4 * 16,
                 q4 < 2);
#pragma unroll
        for (int j = 0; j < 32; ++j) {
            int n = n0 + j;
            KT[n * 64 + (((i >> 3) ^ (n & 7)) << 3) + (i & 7)] = f2bf(vals[j]);
        }
        ushort* kd = kbuf + (size_t)blk * (CHK * DS);
#pragma unroll
        for (int j = 0; j < 4; ++j) {
            int cc = (q4 * 4 + j) ^ (i & 7);
            *(uint4*)&kd[i * 128 + cc * 8] = pack8(&vals[j * 8]);
        }
    }
    {   // V^T builds (raw + coef-scaled) from bf16 zvbf
        int p0 = q4 * 16;
        const ushort* vp = zvbf + (size_t)(row0 + i) * ZV + 2048 + h * HD + p0;
        uint4 a0 = *(const uint4*)vp;
        uint4 a1 = *(const uint4*)(vp + 8);
        unsigned uu[8] = {a0.x, a0.y, a0.z, a0.w, a1.x, a1.y, a1.z, a1.w};
#pragma unroll
        for (int j = 0; j < 8; ++j) {
            ushort v0 = (ushort)(uu[j] & 0xffffu);
            ushort v1 = (ushort)(uu[j] >> 16);
            int p = p0 + 2 * j;
            int addr0 = p * 64 + (((i >> 3) ^ (p & 7)) << 3) + (i & 7);
            int addr1 = (p + 1) * 64 + (((i >> 3) ^ ((p + 1) & 7)) << 3) + (i & 7);
            VT[addr0]  = v0;
            VT[addr1]  = v1;
            cVT[addr0] = f2bf(bf2f(v0) * coef);
            cVT[addr1] = f2bf(bf2f(v1) * coef);
        }
    }
    __syncthreads();
    // export raw VT (coalesced)
    {
        const uint4* vs = (const uint4*)VT;
        uint4* vd = (uint4*)(vtbuf + (size_t)blk * (HD * CHK));
        vd[tid] = vs[tid];
        vd[tid + 256] = vs[tid + 256];
    }
    int wv = tid >> 6, ln = tid & 63, rl = ln & 15, kg = ln >> 4;
    int pA = wv * 16 + rl;
    s8v aV[2];
#pragma unroll
    for (int ks = 0; ks < 2; ++ks)
        aV[ks] = *(const s8v*)&cVT[pA * 64 + (((ks * 4 + kg) ^ (pA & 7)) << 3)];
    f4v dacc[8];
    __builtin_amdgcn_s_setprio(1);
#pragma unroll
    for (int nt = 0; nt < 8; ++nt) {
        int nB = nt * 16 + rl;
        dacc[nt] = f4v{0.f, 0.f, 0.f, 0.f};
#pragma unroll
        for (int ks = 0; ks < 2; ++ks) {
            s8v bK = *(const s8v*)&KT[nB * 64 + (((ks * 4 + kg) ^ (nB & 7)) << 3)];
            dacc[nt] = __builtin_amdgcn_mfma_f32_16x16x32_bf16(aV[ks], bK, dacc[nt], 0, 0, 0);
        }
    }
    __builtin_amdgcn_s_setprio(0);
    __syncthreads();   // all KT reads done
    // bounce Delta through KT space (swizzled [p][n]), then coalesced export
#pragma unroll
    for (int nt = 0; nt < 8; ++nt) {
#pragma unroll
        for (int r = 0; r < 4; ++r) {
            int p = wv * 16 + kg * 4 + r;
            int n = nt * 16 + rl;
            KT[p * 128 + (((n >> 3) ^ (p & 7)) << 3) + (n & 7)] = f2bf(dacc[nt][r]);
        }
    }
    __syncthreads();
    {
        const uint4* dsr = (const uint4*)KT;
        uint4* dd = (uint4*)(dstate + (size_t)blk * (HD * DS));
#pragma unroll
        for (int k = 0; k < 4; ++k) dd[k * 256 + tid] = dsr[k * 256 + tid];
    }
}

// ---------------------------------------------------------------------------
// Chunk-state propagation, bf16 in/out, fp32 carry, in place on dstate.
// 4 n-slices per (b,h) -> 256 blocks. Each thread: one uint4 (8 elems)/chunk.
// ---------------------------------------------------------------------------
__global__ __launch_bounds__(256)
void state_prop(ushort* __restrict__ dstate, const float* __restrict__ rbuf) {
    int g = blockIdx.x;
    size_t bh = (size_t)(g >> 2);
    int sl = g & 3;
    int tid = threadIdx.x;
    float st[8];
#pragma unroll
    for (int j = 0; j < 8; ++j) st[j] = 0.f;
    uint4* base = (uint4*)dstate;
    size_t off0 = bh * NC * 1024ull + (size_t)sl * 256 + tid;
    uint4 nxt = base[off0];
    for (int c = 0; c < NC; ++c) {
        uint4 cur = nxt;
        if (c + 1 < NC) nxt = base[off0 + (size_t)(c + 1) * 1024];
        float r = rbuf[bh * NC + c];
        unsigned uu[4] = {cur.x, cur.y, cur.z, cur.w};
        unsigned oo[4];
#pragma unroll
        for (int e = 0; e < 4; ++e) {
            float d0 = bf_lo(uu[e]), d1 = bf_hi(uu[e]);
            int ix = e * 2;
            oo[e] = (unsigned)f2bf(st[ix]) | ((unsigned)f2bf(st[ix + 1]) << 16);
            st[ix]     = fmaf(r, st[ix], d0);
            st[ix + 1] = fmaf(r, st[ix + 1], d1);
        }
        base[off0 + (size_t)c * 1024] = uint4{oo[0], oo[1], oo[2], oo[3]};
    }
}

// ---------------------------------------------------------------------------
// out: K+VT staged via global_load_lds at start (hidden under Q build);
// P~=mask(QK^T) with recomputed scalars; y = P~V + et*(Q S^T).
// y bounced through LDS -> full-line writes. 40KB LDS -> 4 blocks/CU.
// ---------------------------------------------------------------------------
__global__ __launch_bounds__(256, 4)
void out_kernel(const float* __restrict__ Cn, const float* __restrict__ cosb,
                const float* __restrict__ sinb, const float* __restrict__ ell,
                const float* __restrict__ wbuf, const float* __restrict__ pubuf,
                const float* __restrict__ C_bias, const ushort* __restrict__ dstate,
                const ushort* __restrict__ vtbuf, const ushort* __restrict__ kbuf,
                float* __restrict__ yb) {
    __shared__ __align__(16) ushort Qb[CHK * DS];    // 16KB: Q; then PTb; then y-tile
    __shared__ __align__(16) ushort Kb[CHK * DS];    // 16KB: K staged, then S
    __shared__ __align__(16) ushort VTb[HD * CHK];   // 8KB: V^T [p][t]
    int blk = blockIdx.x;
    int c = blk & (NC - 1);
    int h = (blk >> 5) & (NH - 1);
    int b = blk >> 10;
    int tid = threadIdx.x;
    size_t row0 = (size_t)b * S_LEN + c * CHK;
    size_t bh = (size_t)b * NH + h;
    int i = tid >> 2, q4 = tid & 3;
    int wv2 = tid >> 6, ln = tid & 63;

    // stage K and VT immediately (lands under the Q build)
    {
        const ushort* kg_ = kbuf + (size_t)blk * (CHK * DS);
#pragma unroll
        for (int k = 0; k < 4; ++k) {
            int ch = wv2 * 256 + k * 64;
            __builtin_amdgcn_global_load_lds(
                (const __attribute__((address_space(1))) void*)(kg_ + (size_t)(ch + ln) * 8),
                (__attribute__((address_space(3))) void*)(Kb + ch * 8), 16, 0, 0);
        }
        const ushort* vg = vtbuf + (size_t)blk * (HD * CHK);
#pragma unroll
        for (int k = 0; k < 2; ++k) {
            int ch = wv2 * 128 + k * 64;
            __builtin_amdgcn_global_load_lds(
                (const __attribute__((address_space(1))) void*)(vg + (size_t)(ch + ln) * 8),
                (__attribute__((address_space(3))) void*)(VTb + ch * 8), 16, 0, 0);
        }
    }
    {   // Q build (the only build left)
        int n0 = q4 * 32;
        float vals[32];
        build32v(vals, Cn + (row0 + i) * DS + n0, C_bias + h * DS + n0,
                 cosb + (row0 + i) * NA + q4 * 16, sinb + (row0 + i) * NA + q4 * 16,
                 q4 < 2);
#pragma unroll
        for (int j = 0; j < 4; ++j) {
            int cc = (q4 * 4 + j) ^ (i & 7);
            *(uint4*)&Qb[i * 128 + cc * 8] = pack8(&vals[j * 8]);
        }
    }
    __syncthreads();   // drains K/VT DMA + Q visible

    int rl = ln & 15, kg = ln >> 4;
    int tA = wv2 * 16 + rl;
    s8v aQ[4];
#pragma unroll
    for (int kc = 0; kc < 4; ++kc)
        aQ[kc] = *(const s8v*)&Qb[tA * 128 + (((kc * 4 + kg) ^ (tA & 7)) << 3)];
    f4v pacc[4];
#pragma unroll
    for (int st = 0; st < 4; ++st) pacc[st] = f4v{0.f, 0.f, 0.f, 0.f};
    __builtin_amdgcn_s_setprio(1);
#pragma unroll
    for (int st = 0; st < 4; ++st) {
        int sB = st * 16 + rl;
#pragma unroll
        for (int kc = 0; kc < 4; ++kc) {
            s8v bK = *(const s8v*)&Kb[sB * 128 + (((kc * 4 + kg) ^ (sB & 7)) << 3)];
            pacc[st] = __builtin_amdgcn_mfma_f32_16x16x32_bf16(aQ[kc], bK, pacc[st], 0, 0, 0);
        }
    }
    __builtin_amdgcn_s_setprio(0);
    __syncthreads();   // Kb and Qb free (aQ in regs)

    // issue S load into Kb space (overlaps with mask phase)
    {
        const ushort* sg = dstate + (size_t)blk * (CHK * DS);
#pragma unroll
        for (int k = 0; k < 4; ++k) {
            int ch = wv2 * 256 + k * 64;
            __builtin_amdgcn_global_load_lds(
                (const __attribute__((address_space(1))) void*)(sg + (size_t)(ch + ln) * 8),
                (__attribute__((address_space(3))) void*)(Kb + ch * 8), 16, 0, 0);
        }
    }
    // recompute mask scalars (L2-hot reads, no LDS)
    size_t so0 = bh * S_LEN + c * CHK;
    float basev = (c == 0) ? 0.f : ell[so0 - 1];
    int t2r0 = wv2 * 16 + kg * 4;
    float et[4], wr[4];
#pragma unroll
    for (int r = 0; r < 4; ++r) {
        size_t so = so0 + t2r0 + r;
        et[r] = expf(ell[so] - basev);
        wr[r] = wbuf[so];
    }
    float fs[4];
#pragma unroll
    for (int st = 0; st < 4; ++st) {
        int s = st * 16 + rl;
        size_t sos = so0 + s;
        float u = wbuf[sos];
        if (c * CHK + s < S_LEN - 1) u += pubuf[sos + 1];
        fs[st] = u * expf(fminf(basev - ell[sos], 80.f));
    }
    // mask + pack P~ [t][s] into PTb (= Qb first 8KB)
    ushort* PTb = Qb;
#pragma unroll
    for (int st = 0; st < 4; ++st) {
        int s = st * 16 + rl;
#pragma unroll
        for (int r = 0; r < 4; ++r) {
            int t2 = t2r0 + r;
            float m;
            if (s < t2)       m = et[r] * fs[st];
            else if (s == t2) m = wr[r];
            else              m = 0.f;
            PTb[t2 * 64 + (((s >> 3) ^ (t2 & 7)) << 3) + (s & 7)] = f2bf(pacc[st][r] * m);
        }
    }
    __syncthreads();   // drains S DMA + PTb visible

    s8v aP[2];
#pragma unroll
    for (int ks = 0; ks < 2; ++ks)
        aP[ks] = *(const s8v*)&PTb[tA * 64 + (((ks * 4 + kg) ^ (tA & 7)) << 3)];
    f4v y1[4], y2[4];
#pragma unroll
    for (int pt = 0; pt < 4; ++pt) { y1[pt] = f4v{0.f,0.f,0.f,0.f}; y2[pt] = f4v{0.f,0.f,0.f,0.f}; }
    __builtin_amdgcn_s_setprio(1);
#pragma unroll
    for (int pt = 0; pt < 4; ++pt) {
        int pB = pt * 16 + rl;
#pragma unroll
        for (int ks = 0; ks < 2; ++ks) {
            s8v bV = *(const s8v*)&VTb[pB * 64 + (((ks * 4 + kg) ^ (pB & 7)) << 3)];
            y1[pt] = __builtin_amdgcn_mfma_f32_16x16x32_bf16(aP[ks], bV, y1[pt], 0, 0, 0);
        }
#pragma unroll
        for (int kc = 0; kc < 4; ++kc) {
            s8v bS = *(const s8v*)&Kb[pB * 128 + (((kc * 4 + kg) ^ (pB & 7)) << 3)];
            y2[pt] = __builtin_amdgcn_mfma_f32_16x16x32_bf16(aQ[kc], bS, y2[pt], 0, 0, 0);
        }
    }
    __builtin_amdgcn_s_setprio(0);
    // bounce y tile through Qb (64x64 f32 = 16KB), then coalesced write
    __syncthreads();   // all LDS reads done
    float* ct = (float*)Qb;
#pragma unroll
    for (int pt = 0; pt < 4; ++pt) {
#pragma unroll
        for (int r = 0; r < 4; ++r) {
            int t2 = t2r0 + r;
            int p = pt * 16 + rl;
            ct[t2 * 64 + p] = y1[pt][r] + et[r] * y2[pt][r];
        }
    }
    __syncthreads();
    {
        float* yp = yb + (size_t)blk * (CHK * HD);
        const float4* fsrc = (const float4*)ct;
#pragma unroll
        for (int k = 0; k < 4; ++k) {
            int idx = k * 256 + tid;
            *(float4*)(yp + idx * 4) = fsrc[idx];
        }
    }
}

// ---------------------------------------------------------------------------
// ynorm: y = yb(blocked) + D*v; rmsnorm * w * silu(z) -> bf16 swizzled.
// ---------------------------------------------------------------------------
__global__ __launch_bounds__(256)
void ynorm_kernel(const float* __restrict__ yb, const ushort* __restrict__ zvbf,
                  const float* __restrict__ w, const float* __restrict__ D_param,
                  ushort* __restrict__ ybf) {
    size_t row = blockIdx.x;
    int b = (int)(row >> 11);
    int s = (int)(row & 2047);
    int c = s >> 6, t = s & 63;
    int tid = threadIdx.x;
    int hh = tid >> 3;                 // head for this thread's 8 cols
    int p0 = (tid * 8) & 63;
    const float* yr = yb + (((size_t)(b * NH + hh) * NC + c) * CHK + t) * HD + p0;
    float4 v0 = *(const float4*)yr;
    float4 v1 = *(const float4*)(yr + 4);
    float vvf[8];
    unpack8(*(const uint4*)(zvbf + row * (size_t)ZV + 2048 + tid * 8), vvf);
    float Dp = D_param[hh];
    float yv[8] = {v0.x + Dp * vvf[0], v0.y + Dp * vvf[1], v0.z + Dp * vvf[2], v0.w + Dp * vvf[3],
                   v1.x + Dp * vvf[4], v1.y + Dp * vvf[5], v1.z + Dp * vvf[6], v1.w + Dp * vvf[7]};
    float ss = 0.f;
#pragma unroll
    for (int e = 0; e < 8; ++e) ss += yv[e] * yv[e];
#pragma unroll
    for (int off = 32; off >= 1; off >>= 1) ss += __shfl_xor(ss, off);
    __shared__ float red[4];
    if ((tid & 63) == 0) red[tid >> 6] = ss;
    __syncthreads();
    float tot = red[0] + red[1] + red[2] + red[3];
    float rinv = 1.f / sqrtf(tot * (1.f / 2048.f) + 1e-5f);
    float zv[8];
    unpack8(*(const uint4*)(zvbf + row * (size_t)ZV + tid * 8), zv);
    float4 w0 = *(const float4*)(w + tid * 8);
    float4 w1 = *(const float4*)(w + tid * 8 + 4);
    float wv[8] = {w0.x, w0.y, w0.z, w0.w, w1.x, w1.y, w1.z, w1.w};
    ushort u[8];
#pragma unroll
    for (int e = 0; e < 8; ++e) {
        float sil = zv[e] / (1.f + expf(-zv[e]));
        u[e] = f2bf(yv[e] * rinv * wv[e] * sil);
    }
    int dstc = (tid & ~7) | ((tid & 7) ^ ((int)row & 7));
    uint4 o;
    o.x = (unsigned)u[0] | ((unsigned)u[1] << 16);
    o.y = (unsigned)u[2] | ((unsigned)u[3] << 16);
    o.z = (unsigned)u[4] | ((unsigned)u[5] << 16);
    o.w = (unsigned)u[6] | ((unsigned)u[7] << 16);
    *(uint4*)(ybf + row * (size_t)DI + dstc * 8) = o;
}

// ---------------------------------------------------------------------------
extern "C" void kernel_launch(void* const* d_in, const int* in_sizes, int n_in,
                              void* d_out, int out_size, void* d_ws, size_t ws_size,
                              hipStream_t stream) {
    const float* x          = (const float*)d_in[0];
    const float* W_in       = (const float*)d_in[1];
    const float* dt_bias    = (const float*)d_in[2];
    const float* B_norm_w   = (const float*)d_in[3];
    const float* C_norm_w   = (const float*)d_in[4];
    const float* B_bias     = (const float*)d_in[5];
    const float* C_bias     = (const float*)d_in[6];
    const float* D_param    = (const float*)d_in[7];
    const float* out_norm_w = (const float*)d_in[8];
    const float* W_out      = (const float*)d_in[9];
    float* out = (float*)d_out;

    const size_t M = (size_t)NBATCH * S_LEN;       // 4096
    const size_t NBLK = (size_t)NBATCH * NH * NC;  // 2048
    float* ws = (float*)d_ws;
    size_t off = 0;
    float* projS = ws + off; off += M * PS;            // fp32 scalar cols
    float* cosb  = ws + off; off += M * NA;
    float* sinb  = ws + off; off += M * NA;
    float* Bn    = ws + off; off += M * DS;
    float* Cn    = ws + off; off += M * DS;
    float* ell   = ws + off; off += (size_t)NBATCH * NH * S_LEN;
    float* wbuf  = ws + off; off += (size_t)NBATCH * NH * S_LEN;
    float* pubuf = ws + off; off += (size_t)NBATCH * NH * S_LEN;
    float* yb    = ws + off; off += NBLK * CHK * HD;   // blocked y_partial
    float* rbuf  = ws + off; off += NBLK;
    ushort* zvbf = (ushort*)(ws + off); off += M * ZV / 2;   // z|v bf16
    ushort* xbf  = (ushort*)(ws + off); off += M * DMODEL / 2;
    ushort* wibf = (ushort*)(ws + off); off += (size_t)PDIM * DMODEL / 2;
    ushort* wobf = (ushort*)(ws + off); off += (size_t)DMODEL * DI / 2;
    ushort* ybf  = (ushort*)(ws + off); off += M * DI / 2;
    ushort* dstate = (ushort*)(ws + off); off += NBLK * CHK * DS / 2;
    ushort* vtbuf  = (ushort*)(ws + off); off += NBLK * HD * CHK / 2;
    ushort* kbuf   = (ushort*)(ws + off); off += NBLK * CHK * DS / 2;

    // 0) fused fp32 -> bf16 (swizzled) conversions
    f2bf_all<<<dim3((NCX + NCWI + NCWO) / 256), 256, 0, stream>>>(
        x, W_in, W_out, xbf, wibf, wobf);
    // 1) proj = x @ W_in^T : cols<4096 -> zvbf bf16, cols>=4096 -> projS fp32
    gemm_bf16<<<dim3((PDIM / 128) * (int)(M / 128)), 256, 0, stream>>>(
        xbf, wibf, projS, zvbf, (int)M, PDIM, DMODEL, ZV, PS, 5);
    // 2) phase cumsum -> cos/sin
    phase_kernel<<<dim3(NBATCH * NA), 256, 0, stream>>>(projS, cosb, sinb);
    // 3) per-row prep
    prep_kernel<<<dim3((int)M), 128, 0, stream>>>(projS, dt_bias, B_norm_w, C_norm_w,
                                                  cosb, sinb, Bn, Cn, ell, wbuf, pubuf);
    // 4) cumsum of log-decay
    lcum_kernel<<<dim3(NBATCH * NH), 256, 0, stream>>>(ell);
    // 5) per-chunk delta states + VT/K export
    delta_kernel<<<dim3((int)NBLK), 256, 0, stream>>>(zvbf, Bn, cosb, sinb, ell,
                                                      wbuf, pubuf, B_bias, dstate,
                                                      vtbuf, kbuf, rbuf);
    // 6) chunk-state propagation (bf16, in place, 4 slices/bh)
    state_prop<<<dim3(NBATCH * NH * 4), 256, 0, stream>>>(dstate, rbuf);
    // 7) per-chunk outputs (staged K/VT/S, Q-build only)
    out_kernel<<<dim3((int)NBLK), 256, 0, stream>>>(Cn, cosb, sinb, ell,
                                                    wbuf, pubuf, C_bias,
                                                    dstate, vtbuf, kbuf, yb);
    // 8) y = rmsnorm(yb + D*v)*w*silu(z) -> bf16 swizzled
    ynorm_kernel<<<dim3((int)M), 256, 0, stream>>>(yb, zvbf, out_norm_w, D_param, ybf);
    // 9) out = y @ W_out^T (all fp32 out)
    gemm_bf16<<<dim3((DMODEL / 128) * (int)(M / 128)), 256, 0, stream>>>(
        ybf, wobf, out, nullptr, (int)M, DMODEL, DI, 0, DMODEL, 4);
}